// Round 1
// baseline (55.711 us; speedup 1.0000x reference)
//
#include <hip/hip_runtime.h>

// Problem constants (from reference): x[B=16, S=4096, D=512] f32,
// pe[1, 5000, 512] f32 (only first S rows used), param unused,
// quantum_weight scalar.
constexpr int D = 512;
constexpr int S = 4096;
constexpr int B = 16;
constexpr int ROWS = B * S;            // 65536 rows, one wave each
constexpr int WAVES_PER_BLOCK = 4;     // 256-thread blocks

// One 64-lane wave handles one row of D=512 elements: 8 contiguous floats
// per lane (two float4 loads). cumprod along D via local product + wave
// inclusive-scan (shfl_up) + local replay.
__global__ __launch_bounds__(256) void qpe_kernel(
    const float* __restrict__ x, const float* __restrict__ pe,
    const float* __restrict__ qw, float* __restrict__ out)
{
    const int lane = threadIdx.x & 63;
    const int wid  = threadIdx.x >> 6;
    const int row  = blockIdx.x * WAVES_PER_BLOCK + wid;   // ROWS % 4 == 0
    const int s    = row & (S - 1);                        // position in sequence

    // w = sigmoid(quantum_weight[0]); scalar, L2-cached broadcast load.
    const float w   = 1.0f / (1.0f + __expf(-qw[0]));
    const float omw = 1.0f - w;

    const size_t base = (size_t)row * D + (size_t)lane * 8;
    const float4* xp = (const float4*)(x + base);
    const float4* pp = (const float4*)(pe + (size_t)s * D + (size_t)lane * 8);

    const float4 x0 = xp[0], x1 = xp[1];
    const float4 p0 = pp[0], p1 = pp[1];

    float o[8] = { x0.x + p0.x, x0.y + p0.y, x0.z + p0.z, x0.w + p0.w,
                   x1.x + p1.x, x1.y + p1.y, x1.z + p1.z, x1.w + p1.w };

    // |o| <= ~7 so hardware cos (revolutions-based __cosf) is plenty accurate.
    float c[8];
    #pragma unroll
    for (int j = 0; j < 8; ++j) c[j] = __cosf(o[j]);

    // Local product of this lane's 8 cosines.
    float p = c[0];
    #pragma unroll
    for (int j = 1; j < 8; ++j) p *= c[j];

    // Inclusive multiply-scan across the 64-lane wave (6 shfl_up steps).
    #pragma unroll
    for (int off = 1; off < 64; off <<= 1) {
        float n = __shfl_up(p, off, 64);
        if (lane >= off) p *= n;
    }
    // Exclusive prefix for this lane's chunk.
    float prefix = __shfl_up(p, 1, 64);
    if (lane == 0) prefix = 1.0f;

    // Replay local multiplies to produce the cumprod, blend, store.
    float run = prefix;
    float r[8];
    #pragma unroll
    for (int j = 0; j < 8; ++j) {
        run *= c[j];                 // cumprod(cos(out)) at element j
        r[j] = w * run + omw * o[j];
    }

    float4* op = (float4*)(out + base);
    op[0] = make_float4(r[0], r[1], r[2], r[3]);
    op[1] = make_float4(r[4], r[5], r[6], r[7]);
}

extern "C" void kernel_launch(void* const* d_in, const int* in_sizes, int n_in,
                              void* d_out, int out_size, void* d_ws, size_t ws_size,
                              hipStream_t stream) {
    const float* x  = (const float*)d_in[0];   // [B, S, D]
    const float* pe = (const float*)d_in[1];   // [1, 5000, D]
    // d_in[2] = param (unused by the closed form)
    const float* qw = (const float*)d_in[3];   // [1]
    float* out = (float*)d_out;                // [B, S, D]

    const int blocks = ROWS / WAVES_PER_BLOCK; // 16384
    qpe_kernel<<<blocks, WAVES_PER_BLOCK * 64, 0, stream>>>(x, pe, qw, out);
}

// Round 3
// 55.109 us; speedup vs baseline: 1.0109x; 1.0109x over previous
//
#include <hip/hip_runtime.h>

// out = w*cumprod(cos(x+pe), axis=-1) + (1-w)*(x+pe)
// x[B=16,S=4096,D=512] f32, pe[1,5000,512] f32, qw scalar. param unused.
constexpr int D = 512;
constexpr int S = 4096;
constexpr int B = 16;
constexpr int ROWS = B * S;            // 65536
constexpr int WAVES_PER_BLOCK = 4;     // 256-thread blocks
constexpr int ROWS_PER_WAVE  = 2;      // ILP: two independent scan chains

// Native clang vector type — works with __builtin_nontemporal_store.
typedef float fx4 __attribute__((ext_vector_type(4)));

// --- DPP multiply-scan helpers (gfx9 lineage: row_shr / row_bcast / wave_shr) ---
// update_dpp(old, src, ctrl, row_mask, bank_mask, bound_ctrl=false):
// invalid/masked lanes yield `old`; we pass old = 1.0f (multiplicative identity).
template<int CTRL, int ROW_MASK>
__device__ __forceinline__ float dpp_mul(float x) {
    int t = __builtin_amdgcn_update_dpp(0x3f800000, __float_as_int(x),
                                        CTRL, ROW_MASK, 0xF, false);
    return x * __int_as_float(t);
}

// Inclusive multiply-scan across 64 lanes: 6 VALU DPP ops (no LDS pipe).
__device__ __forceinline__ float wave_incl_mul_scan(float p) {
    p = dpp_mul<0x111, 0xF>(p);   // row_shr:1
    p = dpp_mul<0x112, 0xF>(p);   // row_shr:2
    p = dpp_mul<0x114, 0xF>(p);   // row_shr:4
    p = dpp_mul<0x118, 0xF>(p);   // row_shr:8
    p = dpp_mul<0x142, 0xA>(p);   // row_bcast:15 -> rows 1,3
    p = dpp_mul<0x143, 0xC>(p);   // row_bcast:31 -> rows 2,3
    return p;
}

// Shift whole wave right by 1 (lane0 gets identity 1.0): exclusive prefix.
__device__ __forceinline__ float wave_shr1_id(float p) {
    int t = __builtin_amdgcn_update_dpp(0x3f800000, __float_as_int(p),
                                        0x138 /*wave_shr:1*/, 0xF, 0xF, false);
    return __int_as_float(t);
}

__global__ __launch_bounds__(256) void qpe_kernel(
    const fx4* __restrict__ x4, const fx4* __restrict__ pe4,
    const float* __restrict__ qw, fx4* __restrict__ out4)
{
    const int lane = threadIdx.x & 63;
    const int wid  = threadIdx.x >> 6;
    const int wave = blockIdx.x * WAVES_PER_BLOCK + wid;
    const int row0 = wave * ROWS_PER_WAVE;

    const float w   = 1.0f / (1.0f + __expf(-qw[0]));
    const float omw = 1.0f - w;

    // Issue all global loads up front (2 rows x 2 fx4 each of x and pe).
    fx4 xv[2][2], pv[2][2];
    size_t xb[2];
    #pragma unroll
    for (int r = 0; r < ROWS_PER_WAVE; ++r) {
        const int row = row0 + r;
        const int s   = row & (S - 1);             // rows never cross batch bound
        xb[r] = (size_t)row * (D / 4) + (size_t)lane * 2;
        const size_t pb = (size_t)s * (D / 4) + (size_t)lane * 2;
        xv[r][0] = x4[xb[r]];     xv[r][1] = x4[xb[r] + 1];
        pv[r][0] = pe4[pb];       pv[r][1] = pe4[pb + 1];
    }

    float o[2][8], c[2][8], p[2];
    #pragma unroll
    for (int r = 0; r < ROWS_PER_WAVE; ++r) {
        #pragma unroll
        for (int j = 0; j < 4; ++j) {
            o[r][j]     = xv[r][0][j] + pv[r][0][j];
            o[r][4 + j] = xv[r][1][j] + pv[r][1][j];
        }
        #pragma unroll
        for (int j = 0; j < 8; ++j) c[r][j] = __cosf(o[r][j]);
        float q = c[r][0];
        #pragma unroll
        for (int j = 1; j < 8; ++j) q *= c[r][j];
        p[r] = q;
    }

    // Two independent DPP scans — compiler interleaves them (pure VALU).
    #pragma unroll
    for (int r = 0; r < ROWS_PER_WAVE; ++r) {
        p[r] = wave_incl_mul_scan(p[r]);
        p[r] = wave_shr1_id(p[r]);                 // exclusive prefix, lane0=1
    }

    #pragma unroll
    for (int r = 0; r < ROWS_PER_WAVE; ++r) {
        float run = p[r];
        float res[8];
        #pragma unroll
        for (int j = 0; j < 8; ++j) {
            run *= c[r][j];
            res[j] = w * run + omw * o[r][j];
        }
        fx4 s0 = { res[0], res[1], res[2], res[3] };
        fx4 s1 = { res[4], res[5], res[6], res[7] };
        // Non-temporal: don't let the 134 MB output stream evict x from L3.
        __builtin_nontemporal_store(s0, &out4[xb[r]]);
        __builtin_nontemporal_store(s1, &out4[xb[r] + 1]);
    }
}

extern "C" void kernel_launch(void* const* d_in, const int* in_sizes, int n_in,
                              void* d_out, int out_size, void* d_ws, size_t ws_size,
                              hipStream_t stream) {
    const fx4* x  = (const fx4*)d_in[0];
    const fx4* pe = (const fx4*)d_in[1];
    // d_in[2] = param (unused by the closed form)
    const float* qw  = (const float*)d_in[3];
    fx4* out = (fx4*)d_out;

    const int blocks = ROWS / (WAVES_PER_BLOCK * ROWS_PER_WAVE); // 8192
    qpe_kernel<<<blocks, WAVES_PER_BLOCK * 64, 0, stream>>>(x, pe, qw, out);
}